// Round 16
// baseline (5502.948 us; speedup 1.0000x reference)
//
#include <hip/hip_runtime.h>

typedef unsigned short u16;
typedef __attribute__((ext_vector_type(8))) short short8;
typedef __attribute__((ext_vector_type(4))) float f32x4;

#define DEV __device__ __forceinline__

// B=192, T=64, ACT=16, EMB=1024, STOCH=32, DETER=600, HID=600
// out row stride 1392: [mean_po 0, std_po 32, stoch_po 64, deter 96,
//                       mean_pr 696, std_pr 728, stoch_pr 760, deter 792]
// xd row [192][1280]: [x 0..599 (t=0 only) | deter 600..1199 | pad]
#define XDS 1280
#define PN 1808        // parts / pl bf16 row stride
#define POLL_CAP 65536

DEV u16 f2bf(float f) {
  unsigned u = __float_as_uint(f);
  u = (u + 0x7FFFu + ((u >> 16) & 1u)) >> 16;
  return (u16)u;
}
DEV float bf2f(u16 h) { return __uint_as_float(((unsigned)h) << 16); }
DEV float sigf(float x) { return 1.f / (1.f + __expf(-x)); }
DEV float eluf(float x) { return x > 0.f ? x : __expf(x) - 1.f; }
DEV f32x4 MF(short8 a, short8 b, f32x4 c) {
  return __builtin_amdgcn_mfma_f32_16x16x32_bf16(a, b, c, 0, 0, 0);
}

// ---- device-scope (MALL-coherent) helpers — r5..r15 replay-validated ----
DEV unsigned long long ald64(const void* p) {
  return __hip_atomic_load((const unsigned long long*)p, __ATOMIC_RELAXED,
                           __HIP_MEMORY_SCOPE_AGENT);
}
DEV short8 ald16B(const u16* p) {
  union { unsigned long long u[2]; short8 v; } x;
  x.u[0] = ald64(p);
  x.u[1] = ald64(p + 4);
  return x.v;
}
DEV void ast32(void* p, unsigned v) {
  __hip_atomic_store((unsigned*)p, v, __ATOMIC_RELAXED, __HIP_MEMORY_SCOPE_AGENT);
}
DEV unsigned fld(const unsigned* p) {
  return __hip_atomic_load(p, __ATOMIC_RELAXED, __HIP_MEMORY_SCOPE_AGENT);
}
DEV void fst(unsigned* p, unsigned v) {
  __hip_atomic_store(p, v, __ATOMIC_RELAXED, __HIP_MEMORY_SCOPE_AGENT);
}

// ---------------- f32 -> bf16 with zero row padding (k-major) ----------------
__global__ __launch_bounds__(256) void conv_pad(const float* __restrict__ src,
                                                u16* __restrict__ dst,
                                                int K, int N, int Kpad, int srcRowOff) {
  size_t total = (size_t)Kpad * N;
  for (size_t idx = (size_t)blockIdx.x * 256 + threadIdx.x; idx < total;
       idx += (size_t)gridDim.x * 256) {
    int k = (int)(idx / (size_t)N);
    int n = (int)(idx % (size_t)N);
    dst[idx] = (k < K) ? f2bf(src[(size_t)(k + srcRowOff) * N + n]) : (u16)0;
  }
}

// -------- f32 [K0][N0] (row offset kOff) -> bf16 transposed [Npad][Kpad] -----
__global__ __launch_bounds__(256) void conv_T(const float* __restrict__ src,
                                              u16* __restrict__ dst,
                                              int K0, int N0, int Kpad, int Npad,
                                              int kOff) {
  size_t total = (size_t)Npad * Kpad;
  for (size_t idx = (size_t)blockIdx.x * 256 + threadIdx.x; idx < total;
       idx += (size_t)gridDim.x * 256) {
    int n = (int)(idx / (size_t)Kpad);
    int k = (int)(idx % (size_t)Kpad);
    dst[idx] = (k < K0 && n < N0) ? f2bf(src[(size_t)(k + kOff) * N0 + n]) : (u16)0;
  }
}

// ---- bias row: wxT[n][600] = grub[n]  (consumed via constant-1 K element) ----
__global__ __launch_bounds__(256) void conv_brow(const float* __restrict__ g,
                                                 u16* __restrict__ wxT) {
  int n = blockIdx.x * 256 + threadIdx.x;
  if (n < 1800) wxT[(size_t)n * 608 + 600] = f2bf(g[n]);
}

// ---------------- MFMA 64x64 tile core (setup/tail GEMMs) ----
DEV void mfma_tile(const u16 (*As)[72], const u16 (*Bs)[72], int wm, int wn,
                   int lane, f32x4 acc[2][2]) {
#pragma unroll
  for (int s = 0; s < 2; ++s) {
    const int ko = s * 32 + ((lane >> 4) << 3);
    short8 a0 = *reinterpret_cast<const short8*>(&As[wm + (lane & 15)][ko]);
    short8 a1 = *reinterpret_cast<const short8*>(&As[wm + 16 + (lane & 15)][ko]);
    short8 b0 = *reinterpret_cast<const short8*>(&Bs[wn + (lane & 15)][ko]);
    short8 b1 = *reinterpret_cast<const short8*>(&Bs[wn + 16 + (lane & 15)][ko]);
    acc[0][0] = MF(a0, b0, acc[0][0]);
    acc[0][1] = MF(a0, b1, acc[0][1]);
    acc[1][0] = MF(a1, b0, acc[1][0]);
    acc[1][1] = MF(a1, b1, acc[1][1]);
  }
}

// ---------------- generic 64x64-tiled bf16 GEMM (setup/tail) ----------------
// EPI: 2 = +bias, elu, bf16 out ; 4 = +bias, bf16 out, epre-permuted store
template <int EPI>
__global__ __launch_bounds__(256) void gemm64(
    const u16* __restrict__ A, int lda, const u16* __restrict__ W, int ldw,
    const float* __restrict__ bias, void* __restrict__ Cv, int ldc,
    int Nstore, int N, int K) {
  __shared__ u16 As[64][72];
  __shared__ u16 Bs[64][72];
  const int tid = threadIdx.x, lane = tid & 63, wave = tid >> 6;
  const int wm = (wave & 1) * 32, wn = (wave >> 1) * 32;
  const int bn0 = blockIdx.x * 64, bm0 = blockIdx.y * 64;
  const int am = tid >> 2, ak0 = (tid & 3) * 16;
  const int bk = tid >> 3, bn = (tid & 7) * 8;

  f32x4 acc[2][2] = {};
  for (int k0 = 0; k0 < K; k0 += 64) {
    __syncthreads();
    {
      const u16* src = A + (size_t)(bm0 + am) * lda + k0 + ak0;
      *reinterpret_cast<short8*>(&As[am][ak0]) = *reinterpret_cast<const short8*>(src);
      *reinterpret_cast<short8*>(&As[am][ak0 + 8]) = *reinterpret_cast<const short8*>(src + 8);
    }
    {
      int gn = bn0 + bn;
#pragma unroll
      for (int h = 0; h < 2; ++h) {
        int kk = k0 + bk + h * 32;
        short8 v;
        if (gn + 7 < N) {
          v = *reinterpret_cast<const short8*>(W + (size_t)kk * ldw + gn);
        } else {
          for (int j = 0; j < 8; ++j)
            v[j] = (gn + j < N) ? (short)W[(size_t)kk * ldw + gn + j] : (short)0;
        }
#pragma unroll
        for (int j = 0; j < 8; ++j) Bs[bn + j][bk + h * 32] = (u16)v[j];
      }
    }
    __syncthreads();
    mfma_tile(As, Bs, wm, wn, lane, acc);
  }

#pragma unroll
  for (int r = 0; r < 2; ++r)
#pragma unroll
    for (int c = 0; c < 2; ++c)
#pragma unroll
      for (int i = 0; i < 4; ++i) {
        int grow = bm0 + wm + r * 16 + ((lane >> 4) << 2) + i;
        int gcol = bn0 + wn + c * 16 + (lane & 15);
        if (gcol >= Nstore) continue;
        bool ok = gcol < N;
        float v = acc[r][c][i] + (ok ? bias[gcol] : 0.f);
        if (EPI == 2) {
          v = eluf(v);
          ((u16*)Cv)[(size_t)grow * ldc + gcol] = ok ? f2bf(v) : (u16)0;
        } else {  // EPI 4: epre[t][b][600] layout
          size_t row2 = (size_t)(grow & 63) * 192 + (size_t)(grow >> 6);
          ((u16*)Cv)[row2 * 600 + gcol] = f2bf(v);
        }
      }
}

// ------- init: x(t=0)=elu(action part), deter=0, pads=0, flags=0 ----------
__global__ __launch_bounds__(256) void k_init(const float* __restrict__ action,
                                              const float* __restrict__ img1w,
                                              const float* __restrict__ img1b,
                                              u16* __restrict__ xd,
                                              unsigned* __restrict__ flags) {
  __shared__ float act[16];
  int b = blockIdx.x, tid = threadIdx.x;
  if (b == 0)
    for (int i = tid; i < 6912; i += 256) flags[i] = 0;
  if (tid < 16) act[tid] = action[(size_t)b * 64 * 16 + tid];  // t = 0
  __syncthreads();
  for (int h = tid; h < 600; h += 256) {
    float s = img1b[h];
#pragma unroll
    for (int a = 0; a < 16; ++a) s += act[a] * img1w[(size_t)(32 + a) * 600 + h];
    xd[(size_t)b * XDS + h] = f2bf(eluf(s));
  }
  for (int j = tid; j < 680; j += 256) xd[(size_t)b * XDS + 600 + j] = 0;
}

// ---------------- batched prior head (tail; N=64 GEMM + dist outputs) --------
__global__ __launch_bounds__(256) void head_prior(
    const u16* __restrict__ A, const u16* __restrict__ W,
    const float* __restrict__ bias64, const float* __restrict__ noise,
    float* __restrict__ out) {
  __shared__ u16 As[64][72];
  __shared__ u16 Bs[64][72];
  __shared__ float sl[64][68];
  const int tid = threadIdx.x, lane = tid & 63, wave = tid >> 6;
  const int wm = (wave & 1) * 32, wn = (wave >> 1) * 32;
  const int bm0 = blockIdx.x * 64;
  const int am = tid >> 2, ak0 = (tid & 3) * 16;
  const int bk = tid >> 3, bn = (tid & 7) * 8;

  f32x4 acc[2][2] = {};
  for (int k0 = 0; k0 < 640; k0 += 64) {
    __syncthreads();
    {
      const u16* src = A + (size_t)(bm0 + am) * 640 + k0 + ak0;
      *reinterpret_cast<short8*>(&As[am][ak0]) = *reinterpret_cast<const short8*>(src);
      *reinterpret_cast<short8*>(&As[am][ak0 + 8]) = *reinterpret_cast<const short8*>(src + 8);
    }
#pragma unroll
    for (int h = 0; h < 2; ++h) {
      int kk = k0 + bk + h * 32;
      short8 v = *reinterpret_cast<const short8*>(W + (size_t)kk * 64 + bn);
#pragma unroll
      for (int j = 0; j < 8; ++j) Bs[bn + j][bk + h * 32] = (u16)v[j];
    }
    __syncthreads();
    mfma_tile(As, Bs, wm, wn, lane, acc);
  }
#pragma unroll
  for (int r = 0; r < 2; ++r)
#pragma unroll
    for (int c = 0; c < 2; ++c)
#pragma unroll
      for (int i = 0; i < 4; ++i) {
        int col = wn + c * 16 + (lane & 15);
        sl[wm + r * 16 + ((lane >> 4) << 2) + i][col] = acc[r][c][i] + bias64[col];
      }
  __syncthreads();
  for (int task = tid; task < 64 * 32; task += 256) {
    int r = task >> 5, j = task & 31;
    size_t orow = (size_t)(bm0 + r);
    size_t base = orow * 1392 + 696;
    float mean = sl[r][j];
    float sd = 2.f * sigf(0.5f * sl[r][32 + j]) + 0.1f;
    float st = mean + sd * noise[orow * 32 + j];
    out[base + j] = mean;
    out[base + 32 + j] = sd;
    out[base + 64 + j] = st;
  }
}

// ---- scan: 6 pipelines {8 XCD-pinned deter-A-blocks -> 2 BD-blocks}. -------
// A-block (h,x): deter-half GRU GEMM only (K=608 via wdT), waits FD only.
// BD-block b: gather-ADD deter parts into local x-parts (pl), LN, deter out,
// obs1/obs2/head, img1 -> x into LDS, local xGEMM (wxT, bias row) -> pl.
// Flags: FA 0..47, FD 96+b (256 B apart, device-scope). No xF.
struct ScanArgs {
  u16* xd;            // [192][1280]: x (t=0) + deter carry
  u16* parts;         // [192][PN] bf16 deter-partials from A
  const u16* wdT;     // [1808][608] deter-half weights (XCD-sliced, L2-resident)
  const u16* wxT;     // [1808][608] x-half weights + bias row k=600
  const float* lns;
  const float* lnb;
  u16* dall;          // [12288][640] (nt; read by tail)
  float* out;
  const u16* o1wT;    // [608][608]
  const u16* epre;    // [64][192][600] (t-major, nt loads)
  const u16* o2wT;    // [64][608]
  const float* obs2b;
  const float* npo;
  const u16* w1pT;    // [640][64]
  const float* img1b;
  const float* action;
  unsigned* flags;
};

__global__ __launch_bounds__(1024, 1) void scan64(ScanArgs A) {
  const int bid = blockIdx.x, tid = threadIdx.x;
  const int lane = tid & 63, wave = tid >> 6;
  const int l15 = lane & 15;
  const int koff = (lane >> 4) << 3;   // k-octet offset within 32-k slab
  const int crow = (lane >> 4) << 2;   // C-row base within 16
  __shared__ __align__(16) char smem[143360];
  unsigned* F = A.flags;

  auto FA = [&](int idx) { return F + (size_t)idx * 64; };
  auto FD = [&](int b2) { return F + (size_t)(96 + b2) * 64; };

  if (bid < 48) {
    // ========== A block: deter-half GEMM. h = 32-row half, x = XCD =========
    u16 (*stg)[616] = (u16(*)[616])smem;  // 32 x 616 = 39,424 B
    const int h = bid >> 3, x = bid & 7;
    const int r0 = h * 32;
    const int fl = h * 8 + x;
    const int J = (x == 0) ? 15 : 14;     // wave w < J owns group g = x + 8w
    const bool hasg = (wave < J);
    const int g0 = x + 8 * (hasg ? wave : 0);
    const u16* bp0 = A.wdT + (size_t)(16 * g0 + l15) * 608 + koff;
    const int c0 = 16 * g0 + l15;
    const bool c0ok = hasg && (c0 < 1800);

    for (int t = 0; t < 64; ++t) {
      // deter(t-1) ready when FD >= t (t=0 trivially true)
      if (tid == 0) {
        int it = 0;
        while ((int)min(fld(FD(2 * h)), fld(FD(2 * h + 1))) < t) {
          if (++it > POLL_CAP) break;
          __builtin_amdgcn_s_sleep(1);
        }
      }
      __syncthreads();
      // stage deter: xd cols 600..1207 (octets 0..75 of the deter region)
      for (int idx = tid; idx < 2432; idx += 1024) {
        int r = idx / 76, o = idx - r * 76;
        *reinterpret_cast<short8*>(&stg[r][o * 8]) =
            ald16B(A.xd + (size_t)(r0 + r) * XDS + 600 + o * 8);
      }
      __syncthreads();
      if (hasg) {
        f32x4 p00{}, p01{};
        for (int kk = 0; kk < 608; kk += 32) {
          short8 a0 = *reinterpret_cast<const short8*>(&stg[l15][koff + kk]);
          short8 a1 = *reinterpret_cast<const short8*>(&stg[16 + l15][koff + kk]);
          short8 b0 = *reinterpret_cast<const short8*>(bp0 + kk);
          p00 = MF(a0, b0, p00);
          p01 = MF(a1, b0, p01);
        }
        if (c0ok) {
#pragma unroll
          for (int i = 0; i < 4; ++i) {
            unsigned h00 = f2bf(p00[i]);
            unsigned h10 = f2bf(p01[i]);
            unsigned o00 = (unsigned)__shfl_xor((int)h00, 1);
            unsigned o10 = (unsigned)__shfl_xor((int)h10, 1);
            if (!(lane & 1)) {
              ast32(A.parts + (size_t)(r0 + crow + i) * PN + c0, h00 | (o00 << 16));
              ast32(A.parts + (size_t)(r0 + 16 + crow + i) * PN + c0, h10 | (o10 << 16));
            }
          }
        }
      }
      __syncthreads();  // drains vmcnt per wave -> stores MALL-visible
      if (tid == 0) fst(FA(fl), (unsigned)(t + 1));
    }
  } else {
    // ========== BD block: 16 rows R0..R0+15, 16 waves ======================
    const int b = bid - 48, h = b >> 1;
    const int R0 = b * 16;
    u16 (*pl)[PN] = (u16(*)[PN])smem;                       // 57,856
    float (*dsh)[600] = (float(*)[600])(smem + 57856);      // 38,400
    u16 (*dl)[648] = (u16(*)[648])(smem + 96256);           // 20,736 (deter/x)
    u16 (*hl)[616] = (u16(*)[616])(smem + 116992);          // 19,712
    float (*sl)[68] = (float(*)[68])(smem + 136704);        //  4,352
    u16 (*xa)[72] = (u16(*)[72])(smem + 141056);            //  2,304
    u16* es = (u16*)smem;                                   // overlay on pl

    // local x-half GEMM: dl (x rows, const-1 at k=600) x wxT (+bias row) -> pl
    auto xgemm = [&]() {
      f32x4 xacc[8];
#pragma unroll
      for (int s2 = 0; s2 < 8; ++s2) xacc[s2] = f32x4{0.f, 0.f, 0.f, 0.f};
      for (int kk = 0; kk < 608; kk += 32) {
        short8 a = *reinterpret_cast<const short8*>(&dl[l15][koff + kk]);
#pragma unroll
        for (int s2 = 0; s2 < 8; ++s2) {
          int g2 = wave + 16 * s2;
          if (g2 < 113) {
            const u16* bp = A.wxT + (size_t)(16 * g2 + l15) * 608 + koff + kk;
            xacc[s2] = MF(a, *reinterpret_cast<const short8*>(bp), xacc[s2]);
          }
        }
      }
#pragma unroll
      for (int s2 = 0; s2 < 8; ++s2) {
        int g2 = wave + 16 * s2;
        if (g2 < 113) {
          int c = 16 * g2 + l15;
#pragma unroll
          for (int i = 0; i < 4; ++i) pl[crow + i][c] = f2bf(xacc[s2][i]);
        }
      }
      __syncthreads();
    };

    // init LDS
    for (int i = tid; i < 16 * 648; i += 1024) ((u16*)dl)[i] = 0;
    for (int i = tid; i < 16 * 616; i += 1024) ((u16*)hl)[i] = 0;
    for (int i = tid; i < 16 * 72; i += 1024) ((u16*)xa)[i] = 0;
    for (int i = tid; i < 16 * 600; i += 1024) ((float*)dsh)[i] = 0.f;
    __syncthreads();
    // prologue: x(0) from xd -> dl (cols 0..599), bias-1 at col 600, xGEMM
    for (int idx = tid; idx < 1200; idx += 1024) {
      int r = idx / 75, o = (idx - r * 75) * 8;
      *reinterpret_cast<short8*>(&dl[r][o]) =
          ald16B(A.xd + (size_t)(R0 + r) * XDS + o);
    }
    if (tid < 16) dl[tid][600] = 0x3F80;  // 1.0bf16: picks up bias row of wxT
    __syncthreads();
    xgemm();

    for (int t = 0; t < 64; ++t) {
      // ---- gather-ADD deter parts into pl (per-producer pipelined) ----
      {
        const unsigned tgt = (unsigned)(t + 1);
        const int fw = wave & 7;
        const int rlo = (wave < 8) ? 0 : 8;
        int it = 0;
        while (fld(FA(h * 8 + fw)) < tgt) {
          if (++it > POLL_CAP) break;
          __builtin_amdgcn_s_sleep(1);
        }
        const int J2 = (fw == 0) ? 15 : 14;
        for (int task = lane; task < J2 * 16; task += 64) {
          int j2 = task >> 4;
          int r2 = (task >> 1) & 7, hf = task & 1;
          int col = 16 * (fw + 8 * j2) + hf * 8;
          short8 dv = ald16B(A.parts + (size_t)(R0 + rlo + r2) * PN + col);
          short8 xv = *reinterpret_cast<const short8*>(&pl[rlo + r2][col]);
          short8 sv;
#pragma unroll
          for (int e = 0; e < 8; ++e)
            sv[e] = (short)f2bf(bf2f((u16)xv[e]) + bf2f((u16)dv[e]));
          *reinterpret_cast<short8*>(&pl[rlo + r2][col]) = sv;
        }
      }
      __syncthreads();
      // ---- LN + gates + deter: one row per wave ----
      {
        const int rr = wave;
        float s = 0.f;
        for (int j = lane; j < 1800; j += 64) s += bf2f(pl[rr][j]);
#pragma unroll
        for (int o = 32; o; o >>= 1) s += __shfl_xor(s, o);
        float m = s * (1.f / 1800.f);
        float q2 = 0.f;
        for (int j = lane; j < 1800; j += 64) {
          float d = bf2f(pl[rr][j]) - m;
          q2 += d * d;
        }
#pragma unroll
        for (int o = 32; o; o >>= 1) q2 += __shfl_xor(q2, o);
        float rstd = rsqrtf(q2 * (1.f / 1800.f) + 1e-5f);
        for (int j = lane; j < 600; j += 64) {
          float p0 = (bf2f(pl[rr][j]) - m) * rstd * A.lns[j] + A.lnb[j];
          float p1 = (bf2f(pl[rr][600 + j]) - m) * rstd * A.lns[600 + j] + A.lnb[600 + j];
          float p2 =
              (bf2f(pl[rr][1200 + j]) - m) * rstd * A.lns[1200 + j] + A.lnb[1200 + j];
          float r2 = sigf(p0);
          float cd = tanhf(r2 * p1);
          float u = sigf(p2 - 1.f);
          float dn = u * cd + (1.f - u) * dsh[rr][j];
          dsh[rr][j] = dn;
          dl[rr][j] = f2bf(dn);
          unsigned hv = f2bf(dn);
          unsigned ov = (unsigned)__shfl_xor((int)hv, 1);
          if (!(lane & 1))
            ast32(A.xd + (size_t)(R0 + rr) * XDS + 600 + j, hv | (ov << 16));
        }
      }
      __syncthreads();  // deter xd stores drained -> publish early
      if (tid == 0) fst(FD(b), (unsigned)(t + 1));
      // ---- off-critical-path: out/dall deter streams + epre stage ----
      for (int idx = tid; idx < 4800; idx += 1024) {
        int r = idx / 300, j = (idx - r * 300) * 2;
        float f0 = dsh[r][j], f1 = dsh[r][j + 1];
        unsigned pk = (unsigned)f2bf(f0) | ((unsigned)f2bf(f1) << 16);
        size_t orow = (size_t)(R0 + r) * 64 + t;
        __builtin_nontemporal_store(pk, (unsigned*)(A.dall + orow * 640 + j));
        float* ob = A.out + orow * 1392;
        __builtin_nontemporal_store(f0, ob + 96 + j);
        __builtin_nontemporal_store(f1, ob + 97 + j);
        __builtin_nontemporal_store(f0, ob + 792 + j);
        __builtin_nontemporal_store(f1, ob + 793 + j);
      }
      if (tid < 320) {
        int r = tid / 20, qd = tid - r * 20;
        size_t orow = (size_t)(R0 + r) * 64 + t;
        __builtin_nontemporal_store(0u, (unsigned*)(A.dall + orow * 640 + 600 + 2 * qd));
      }
      for (int idx = tid; idx < 1200; idx += 1024) {  // es overlays dead pl
        int r = idx / 75, ko2 = (idx - r * 75) * 8;
        short8 ev = __builtin_nontemporal_load(
            (const short8*)(A.epre + ((size_t)t * 192 + R0 + r) * 600 + ko2));
        *reinterpret_cast<short8*>(&es[r * 608 + ko2]) = ev;
      }
      __syncthreads();
      // ---- obs1: hl = elu(deter @ o1w + epre)  (3 rounds over 16 waves) ----
#pragma unroll
      for (int s2 = 0; s2 < 3; ++s2) {
        int g2 = wave + 16 * s2;
        if (g2 < 38) {
          const u16* bp = A.o1wT + (size_t)(g2 * 16 + l15) * 608 + koff;
          f32x4 ac{};
          for (int kk = 0; kk < 608; kk += 32)
            ac = MF(*reinterpret_cast<const short8*>(&dl[l15][koff + kk]),
                    *reinterpret_cast<const short8*>(bp + kk), ac);
          int cw = g2 * 16 + l15;
          if (cw < 600) {
#pragma unroll
            for (int i = 0; i < 4; ++i) {
              int r = crow + i;
              hl[r][cw] = f2bf(eluf(ac[i] + bf2f(es[r * 608 + cw])));
            }
          }
        }
      }
      __syncthreads();
      // ---- obs2 (waves 0-3) ----
      if (wave < 4) {
        const int n0 = wave * 16;
        const u16* bp = A.o2wT + (size_t)(n0 + l15) * 608 + koff;
        f32x4 ac{};
        for (int kk = 0; kk < 608; kk += 32)
          ac = MF(*reinterpret_cast<const short8*>(&hl[l15][koff + kk]),
                  *reinterpret_cast<const short8*>(bp + kk), ac);
#pragma unroll
        for (int i = 0; i < 4; ++i)
          sl[crow + i][n0 + l15] = ac[i] + A.obs2b[n0 + l15];
      }
      __syncthreads();
      // ---- head outputs + stoch + xa ----
      if (tid < 512) {
        int r = tid >> 5, j = tid & 31;
        size_t orow = (size_t)(R0 + r) * 64 + t;
        float mean = sl[r][j];
        float sd = 2.f * sigf(0.5f * sl[r][32 + j]) + 0.1f;
        float st =
            mean + sd * __builtin_nontemporal_load((const float*)&A.npo[orow * 32 + j]);
        float* ob = A.out + orow * 1392;
        __builtin_nontemporal_store(mean, ob + j);
        __builtin_nontemporal_store(sd, ob + 32 + j);
        __builtin_nontemporal_store(st, ob + 64 + j);
        xa[r][j] = f2bf(st);
      } else if (tid < 768) {
        int r = (tid - 512) >> 4, a2 = tid & 15;
        float av =
            (t < 63)
                ? __builtin_nontemporal_load(
                      (const float*)&A.action[((size_t)(R0 + r) * 64 + t + 1) * 16 + a2])
                : 0.f;
        xa[r][32 + a2] = f2bf(av);
      }
      __syncthreads();
      // ---- img1 -> x(t+1) into dl (LDS only; col 600 bias-1 untouched) ----
      if (t < 63) {
#pragma unroll
        for (int s2 = 0; s2 < 3; ++s2) {
          int g2 = wave + 16 * s2;
          if (g2 < 38) {
            const u16* bp = A.w1pT + (size_t)(g2 * 16 + l15) * 64 + koff;
            f32x4 ax{};
            ax = MF(*reinterpret_cast<const short8*>(&xa[l15][koff]),
                    *reinterpret_cast<const short8*>(bp), ax);
            ax = MF(*reinterpret_cast<const short8*>(&xa[l15][32 + koff]),
                    *reinterpret_cast<const short8*>(bp + 32), ax);
            int cx = g2 * 16 + l15;
            if (cx < 600) {
              float bi = A.img1b[cx];
#pragma unroll
              for (int i = 0; i < 4; ++i)
                dl[crow + i][cx] = f2bf(eluf(ax[i] + bi));
            }
          }
        }
        __syncthreads();
        // ---- local x-half GEMM for step t+1 -> pl ----
        xgemm();
      }
    }
  }
}

// ---------------- launch ----------------
extern "C" void kernel_launch(void* const* d_in, const int* in_sizes, int n_in,
                              void* d_out, int out_size, void* d_ws, size_t ws_size,
                              hipStream_t stream) {
  (void)in_sizes; (void)n_in; (void)out_size; (void)ws_size;
  const float* action = (const float*)d_in[0];
  const float* embed = (const float*)d_in[1];
  const float* npr = (const float*)d_in[2];
  const float* npo = (const float*)d_in[3];
  const float* img1w = (const float*)d_in[4];
  const float* img1b = (const float*)d_in[5];
  const float* gruw = (const float*)d_in[6];
  const float* grub = (const float*)d_in[7];
  const float* lns = (const float*)d_in[8];
  const float* lnb = (const float*)d_in[9];
  const float* img2w = (const float*)d_in[10];
  const float* img2b = (const float*)d_in[11];
  const float* img3w = (const float*)d_in[12];
  const float* img3b = (const float*)d_in[13];
  const float* obs1w = (const float*)d_in[14];
  const float* obs1b = (const float*)d_in[15];
  const float* obs2w = (const float*)d_in[16];
  const float* obs2b = (const float*)d_in[17];
  float* out = (float*)d_out;
  char* ws = (char*)d_ws;

  size_t off = 0;
  auto alloc = [&](size_t bytes) {
    size_t o = off;
    off += (bytes + 255) & ~(size_t)255;
    return o;
  };
  size_t o_flags = alloc(6912 * 4);
  size_t o_embed = alloc(12288ull * 1024 * 2);  // reused as dall (12288x640)
  size_t o_epre = alloc(12288ull * 600 * 2);    // reused (with o_wemb) as h_img
  size_t o_wemb = alloc(1024ull * 600 * 2);
  size_t o_wxT = alloc(1808ull * 608 * 2);
  size_t o_wdT = alloc(1808ull * 608 * 2);
  size_t o_o1wT = alloc(608ull * 608 * 2);
  size_t o_o2wT = alloc(64ull * 608 * 2);
  size_t o_w1pT = alloc(640ull * 64 * 2);
  size_t o_i2w = alloc(640ull * 600 * 2);
  size_t o_i3w = alloc(640ull * 64 * 2);
  size_t o_xd = alloc(192ull * XDS * 2);
  size_t o_parts = alloc(192ull * PN * 2);

  unsigned* flags = (unsigned*)(ws + o_flags);
  u16* embed_bf = (u16*)(ws + o_embed);
  u16* dall = (u16*)(ws + o_embed);
  u16* epre = (u16*)(ws + o_epre);
  u16* himg = (u16*)(ws + o_epre);
  u16* wemb = (u16*)(ws + o_wemb);
  u16* wxT = (u16*)(ws + o_wxT);
  u16* wdT = (u16*)(ws + o_wdT);
  u16* o1wT = (u16*)(ws + o_o1wT);
  u16* o2wT = (u16*)(ws + o_o2wT);
  u16* w1pT = (u16*)(ws + o_w1pT);
  u16* i2wb = (u16*)(ws + o_i2w);
  u16* i3wb = (u16*)(ws + o_i3w);
  u16* xd = (u16*)(ws + o_xd);
  u16* parts = (u16*)(ws + o_parts);

  auto cgr = [](size_t total) {
    size_t g = (total + 255) / 256;
    return (unsigned)(g > 4096 ? 4096 : g);
  };

  // setup conversions
  conv_pad<<<cgr(12288ull * 1024), 256, 0, stream>>>(embed, embed_bf, 12288, 1024, 12288, 0);
  conv_pad<<<cgr(1024ull * 600), 256, 0, stream>>>(obs1w, wemb, 1024, 600, 1024, 600);
  conv_pad<<<cgr(640ull * 600), 256, 0, stream>>>(img2w, i2wb, 600, 600, 640, 0);
  conv_pad<<<cgr(640ull * 64), 256, 0, stream>>>(img3w, i3wb, 600, 64, 640, 0);
  conv_T<<<cgr(1808ull * 608), 256, 0, stream>>>(gruw, wxT, 600, 1800, 608, 1808, 0);
  conv_T<<<cgr(1808ull * 608), 256, 0, stream>>>(gruw, wdT, 600, 1800, 608, 1808, 600);
  conv_brow<<<8, 256, 0, stream>>>(grub, wxT);
  conv_T<<<cgr(608ull * 608), 256, 0, stream>>>(obs1w, o1wT, 600, 600, 608, 608, 0);
  conv_T<<<cgr(64ull * 608), 256, 0, stream>>>(obs2w, o2wT, 600, 64, 608, 64, 0);
  conv_T<<<cgr(640ull * 64), 256, 0, stream>>>(img1w, w1pT, 48, 600, 64, 640, 0);

  k_init<<<192, 256, 0, stream>>>(action, img1w, img1b, xd, flags);

  // epre[t][b][600] = embed @ obs1_w[600:,:] + obs1_b   (bf16, t-major)
  gemm64<4><<<dim3(10, 192), 256, 0, stream>>>(embed_bf, 1024, wemb, 600, obs1b,
                                               epre, 600, 600, 600, 1024);

  // scan: 48 deter-A blocks + 12 BD blocks, 1024 threads each
  ScanArgs sa;
  sa.xd = xd; sa.parts = parts;
  sa.wdT = wdT; sa.wxT = wxT; sa.lns = lns; sa.lnb = lnb;
  sa.dall = dall; sa.out = out;
  sa.o1wT = o1wT; sa.epre = epre;
  sa.o2wT = o2wT; sa.obs2b = obs2b; sa.npo = npo;
  sa.w1pT = w1pT; sa.img1b = img1b; sa.action = action;
  sa.flags = flags;
  scan64<<<60, 1024, 0, stream>>>(sa);

  // batched prior: h_img = elu(deter_all @ img2_w + img2_b), then img3 head
  gemm64<2><<<dim3(10, 192), 256, 0, stream>>>(dall, 640, i2wb, 600, img2b,
                                               himg, 640, 640, 600, 640);
  head_prior<<<192, 256, 0, stream>>>(himg, i3wb, img3b, npr, out);
}

// Round 17
// 2565.991 us; speedup vs baseline: 2.1446x; 2.1446x over previous
//
#include <hip/hip_runtime.h>

typedef unsigned short u16;
typedef __attribute__((ext_vector_type(8))) short short8;
typedef __attribute__((ext_vector_type(4))) float f32x4;

#define DEV __device__ __forceinline__

// B=192, T=64, ACT=16, EMB=1024, STOCH=32, DETER=600, HID=600
// out row stride 1392: [mean_po 0, std_po 32, stoch_po 64, deter 96,
//                       mean_pr 696, std_pr 728, stoch_pr 760, deter 792]
// xd row [192][1280]: [x 0..599 | deter 600..1199 | pad 1200..1279]
#define XDS 1280
#define PN 1808        // parts bf16 row stride
#define POLL_CAP 65536

DEV u16 f2bf(float f) {
  unsigned u = __float_as_uint(f);
  u = (u + 0x7FFFu + ((u >> 16) & 1u)) >> 16;
  return (u16)u;
}
DEV float bf2f(u16 h) { return __uint_as_float(((unsigned)h) << 16); }
DEV float sigf(float x) { return 1.f / (1.f + __expf(-x)); }
DEV float eluf(float x) { return x > 0.f ? x : __expf(x) - 1.f; }
DEV f32x4 MF(short8 a, short8 b, f32x4 c) {
  return __builtin_amdgcn_mfma_f32_16x16x32_bf16(a, b, c, 0, 0, 0);
}

// ---- device-scope (MALL-coherent) helpers — r5..r15 replay-validated ----
DEV unsigned long long ald64(const void* p) {
  return __hip_atomic_load((const unsigned long long*)p, __ATOMIC_RELAXED,
                           __HIP_MEMORY_SCOPE_AGENT);
}
DEV short8 ald16B(const u16* p) {
  union { unsigned long long u[2]; short8 v; } x;
  x.u[0] = ald64(p);
  x.u[1] = ald64(p + 4);
  return x.v;
}
DEV void ast32(void* p, unsigned v) {
  __hip_atomic_store((unsigned*)p, v, __ATOMIC_RELAXED, __HIP_MEMORY_SCOPE_AGENT);
}
DEV unsigned fld(const unsigned* p) {
  return __hip_atomic_load(p, __ATOMIC_RELAXED, __HIP_MEMORY_SCOPE_AGENT);
}
DEV void fst(unsigned* p, unsigned v) {
  __hip_atomic_store(p, v, __ATOMIC_RELAXED, __HIP_MEMORY_SCOPE_AGENT);
}

// ---------------- f32 -> bf16 with zero row padding (k-major) ----------------
__global__ __launch_bounds__(256) void conv_pad(const float* __restrict__ src,
                                                u16* __restrict__ dst,
                                                int K, int N, int Kpad, int srcRowOff) {
  size_t total = (size_t)Kpad * N;
  for (size_t idx = (size_t)blockIdx.x * 256 + threadIdx.x; idx < total;
       idx += (size_t)gridDim.x * 256) {
    int k = (int)(idx / (size_t)N);
    int n = (int)(idx % (size_t)N);
    dst[idx] = (k < K) ? f2bf(src[(size_t)(k + srcRowOff) * N + n]) : (u16)0;
  }
}

// -------- f32 [K0][N0] (row offset kOff) -> bf16 transposed [Npad][Kpad] -----
__global__ __launch_bounds__(256) void conv_T(const float* __restrict__ src,
                                              u16* __restrict__ dst,
                                              int K0, int N0, int Kpad, int Npad,
                                              int kOff) {
  size_t total = (size_t)Npad * Kpad;
  for (size_t idx = (size_t)blockIdx.x * 256 + threadIdx.x; idx < total;
       idx += (size_t)gridDim.x * 256) {
    int n = (int)(idx / (size_t)Kpad);
    int k = (int)(idx % (size_t)Kpad);
    dst[idx] = (k < K0 && n < N0) ? f2bf(src[(size_t)(k + kOff) * N0 + n]) : (u16)0;
  }
}

// ---- bias row: wxT[n][600] = grub[n]  (consumed via constant-1 K element) ----
__global__ __launch_bounds__(256) void conv_brow(const float* __restrict__ g,
                                                 u16* __restrict__ wxT) {
  int n = blockIdx.x * 256 + threadIdx.x;
  if (n < 1800) wxT[(size_t)n * 608 + 600] = f2bf(g[n]);
}

// ---------------- MFMA 64x64 tile core (setup/tail GEMMs) ----
DEV void mfma_tile(const u16 (*As)[72], const u16 (*Bs)[72], int wm, int wn,
                   int lane, f32x4 acc[2][2]) {
#pragma unroll
  for (int s = 0; s < 2; ++s) {
    const int ko = s * 32 + ((lane >> 4) << 3);
    short8 a0 = *reinterpret_cast<const short8*>(&As[wm + (lane & 15)][ko]);
    short8 a1 = *reinterpret_cast<const short8*>(&As[wm + 16 + (lane & 15)][ko]);
    short8 b0 = *reinterpret_cast<const short8*>(&Bs[wn + (lane & 15)][ko]);
    short8 b1 = *reinterpret_cast<const short8*>(&Bs[wn + 16 + (lane & 15)][ko]);
    acc[0][0] = MF(a0, b0, acc[0][0]);
    acc[0][1] = MF(a0, b1, acc[0][1]);
    acc[1][0] = MF(a1, b0, acc[1][0]);
    acc[1][1] = MF(a1, b1, acc[1][1]);
  }
}

// ---------------- generic 64x64-tiled bf16 GEMM (setup/tail) ----------------
// EPI: 2 = +bias, elu, bf16 out ; 4 = +bias, bf16 out, epre-permuted store
template <int EPI>
__global__ __launch_bounds__(256) void gemm64(
    const u16* __restrict__ A, int lda, const u16* __restrict__ W, int ldw,
    const float* __restrict__ bias, void* __restrict__ Cv, int ldc,
    int Nstore, int N, int K) {
  __shared__ u16 As[64][72];
  __shared__ u16 Bs[64][72];
  const int tid = threadIdx.x, lane = tid & 63, wave = tid >> 6;
  const int wm = (wave & 1) * 32, wn = (wave >> 1) * 32;
  const int bn0 = blockIdx.x * 64, bm0 = blockIdx.y * 64;
  const int am = tid >> 2, ak0 = (tid & 3) * 16;
  const int bk = tid >> 3, bn = (tid & 7) * 8;

  f32x4 acc[2][2] = {};
  for (int k0 = 0; k0 < K; k0 += 64) {
    __syncthreads();
    {
      const u16* src = A + (size_t)(bm0 + am) * lda + k0 + ak0;
      *reinterpret_cast<short8*>(&As[am][ak0]) = *reinterpret_cast<const short8*>(src);
      *reinterpret_cast<short8*>(&As[am][ak0 + 8]) = *reinterpret_cast<const short8*>(src + 8);
    }
    {
      int gn = bn0 + bn;
#pragma unroll
      for (int h = 0; h < 2; ++h) {
        int kk = k0 + bk + h * 32;
        short8 v;
        if (gn + 7 < N) {
          v = *reinterpret_cast<const short8*>(W + (size_t)kk * ldw + gn);
        } else {
          for (int j = 0; j < 8; ++j)
            v[j] = (gn + j < N) ? (short)W[(size_t)kk * ldw + gn + j] : (short)0;
        }
#pragma unroll
        for (int j = 0; j < 8; ++j) Bs[bn + j][bk + h * 32] = (u16)v[j];
      }
    }
    __syncthreads();
    mfma_tile(As, Bs, wm, wn, lane, acc);
  }

#pragma unroll
  for (int r = 0; r < 2; ++r)
#pragma unroll
    for (int c = 0; c < 2; ++c)
#pragma unroll
      for (int i = 0; i < 4; ++i) {
        int grow = bm0 + wm + r * 16 + ((lane >> 4) << 2) + i;
        int gcol = bn0 + wn + c * 16 + (lane & 15);
        if (gcol >= Nstore) continue;
        bool ok = gcol < N;
        float v = acc[r][c][i] + (ok ? bias[gcol] : 0.f);
        if (EPI == 2) {
          v = eluf(v);
          ((u16*)Cv)[(size_t)grow * ldc + gcol] = ok ? f2bf(v) : (u16)0;
        } else {  // EPI 4: epre[t][b][600] layout
          size_t row2 = (size_t)(grow & 63) * 192 + (size_t)(grow >> 6);
          ((u16*)Cv)[row2 * 600 + gcol] = f2bf(v);
        }
      }
}

// ------- init: x(t=0)=elu(action part), deter=0, pads=0, flags=0 ----------
__global__ __launch_bounds__(256) void k_init(const float* __restrict__ action,
                                              const float* __restrict__ img1w,
                                              const float* __restrict__ img1b,
                                              u16* __restrict__ xd,
                                              unsigned* __restrict__ flags) {
  __shared__ float act[16];
  int b = blockIdx.x, tid = threadIdx.x;
  if (b == 0)
    for (int i = tid; i < 11264; i += 256) flags[i] = 0;
  if (tid < 16) act[tid] = action[(size_t)b * 64 * 16 + tid];  // t = 0
  __syncthreads();
  for (int h = tid; h < 600; h += 256) {
    float s = img1b[h];
#pragma unroll
    for (int a = 0; a < 16; ++a) s += act[a] * img1w[(size_t)(32 + a) * 600 + h];
    xd[(size_t)b * XDS + h] = f2bf(eluf(s));
  }
  for (int j = tid; j < 680; j += 256) xd[(size_t)b * XDS + 600 + j] = 0;
}

// ---------------- batched prior head (tail; N=64 GEMM + dist outputs) --------
__global__ __launch_bounds__(256) void head_prior(
    const u16* __restrict__ A, const u16* __restrict__ W,
    const float* __restrict__ bias64, const float* __restrict__ noise,
    float* __restrict__ out) {
  __shared__ u16 As[64][72];
  __shared__ u16 Bs[64][72];
  __shared__ float sl[64][68];
  const int tid = threadIdx.x, lane = tid & 63, wave = tid >> 6;
  const int wm = (wave & 1) * 32, wn = (wave >> 1) * 32;
  const int bm0 = blockIdx.x * 64;
  const int am = tid >> 2, ak0 = (tid & 3) * 16;
  const int bk = tid >> 3, bn = (tid & 7) * 8;

  f32x4 acc[2][2] = {};
  for (int k0 = 0; k0 < 640; k0 += 64) {
    __syncthreads();
    {
      const u16* src = A + (size_t)(bm0 + am) * 640 + k0 + ak0;
      *reinterpret_cast<short8*>(&As[am][ak0]) = *reinterpret_cast<const short8*>(src);
      *reinterpret_cast<short8*>(&As[am][ak0 + 8]) = *reinterpret_cast<const short8*>(src + 8);
    }
#pragma unroll
    for (int h = 0; h < 2; ++h) {
      int kk = k0 + bk + h * 32;
      short8 v = *reinterpret_cast<const short8*>(W + (size_t)kk * 64 + bn);
#pragma unroll
      for (int j = 0; j < 8; ++j) Bs[bn + j][bk + h * 32] = (u16)v[j];
    }
    __syncthreads();
    mfma_tile(As, Bs, wm, wn, lane, acc);
  }
#pragma unroll
  for (int r = 0; r < 2; ++r)
#pragma unroll
    for (int c = 0; c < 2; ++c)
#pragma unroll
      for (int i = 0; i < 4; ++i) {
        int col = wn + c * 16 + (lane & 15);
        sl[wm + r * 16 + ((lane >> 4) << 2) + i][col] = acc[r][c][i] + bias64[col];
      }
  __syncthreads();
  for (int task = tid; task < 64 * 32; task += 256) {
    int r = task >> 5, j = task & 31;
    size_t orow = (size_t)(bm0 + r);
    size_t base = orow * 1392 + 696;
    float mean = sl[r][j];
    float sd = 2.f * sigf(0.5f * sl[r][32 + j]) + 0.1f;
    float st = mean + sd * noise[orow * 32 + j];
    out[base + j] = mean;
    out[base + 32 + j] = sd;
    out[base + 64 + j] = st;
  }
}

// ---- scan: 6 pipelines {8 XCD-pinned A-blocks -> 2 BD-blocks}. -------------
// A-block (h,x), 3-phase pipeline per step:
//   P1 deter-GEMM (stgD holds deter_{t-1} from last P3; zero extra stage),
//   P2 wait xF -> stage x -> x-GEMM (+bias row) -> parts -> FA,
//   P3 wait FD(t+1) -> stage deter_t -> obs1 slice (+epre, elu) -> hobs -> FH.
// BD-block b: gather parts (pipelined) -> LN -> deter -> FD -> streams ->
//   wait FH -> gather hobs -> obs2 -> head -> img1 -> xF.
// Flags (256B apart): FA 0..47, xF 64+b, FD 96+b, FH 128..175.
struct ScanArgs {
  u16* xd;            // [192][1280]
  u16* parts;         // [192][PN] bf16 (bias fused via wxT row)
  u16* hobs;          // [192][640] bf16 obs1 outputs
  const u16* wdT;     // [1808][608] deter-half GRU weights
  const u16* wxT;     // [1808][608] x-half GRU weights + bias row k=600
  const float* lns;
  const float* lnb;
  u16* dall;          // [12288][640] (nt; read by tail)
  float* out;
  const u16* o1wT;    // [608][608]
  const u16* epre;    // [64][192][600] (t-major, nt loads)
  const u16* o2wT;    // [64][608]
  const float* obs2b;
  const float* npo;
  const u16* w1pT;    // [640][64]
  const float* img1b;
  const float* action;
  unsigned* flags;
};

__global__ __launch_bounds__(1024, 1) void scan64(ScanArgs A) {
  const int bid = blockIdx.x, tid = threadIdx.x;
  const int lane = tid & 63, wave = tid >> 6;
  const int l15 = lane & 15;
  const int koff = (lane >> 4) << 3;   // k-octet offset within 32-k slab
  const int crow = (lane >> 4) << 2;   // C-row base within 16
  __shared__ __align__(16) char smem[143360];
  unsigned* F = A.flags;

  auto FA = [&](int idx) { return F + (size_t)idx * 64; };
  auto FX = [&](int b2) { return F + (size_t)(64 + b2) * 64; };
  auto FD = [&](int b2) { return F + (size_t)(96 + b2) * 64; };
  auto FH = [&](int idx) { return F + (size_t)(128 + idx) * 64; };

  if (bid < 48) {
    // ========== A block: h = 32-row half, x = XCD col-comb ==========
    u16 (*stgD)[616] = (u16(*)[616])smem;             // 39,424
    u16 (*stgX)[616] = (u16(*)[616])(smem + 39424);   // 39,424
    const int h = bid >> 3, x = bid & 7;
    const int r0 = h * 32;
    const int fl = h * 8 + x;
    // GRU col-group per wave (113 groups over 8 x-combs)
    const int J = (x == 0) ? 15 : 14;
    const bool hasg = (wave < J);
    const int g0 = x + 8 * (hasg ? wave : 0);
    const u16* bd0 = A.wdT + (size_t)(16 * g0 + l15) * 608 + koff;
    const u16* bx0 = A.wxT + (size_t)(16 * g0 + l15) * 608 + koff;
    const int c0 = 16 * g0 + l15;
    const bool c0ok = hasg && (c0 < 1800);
    // obs1 tiles: x<6 -> 5 groups, else 4; tile = (group, rowhalf)
    const int ng = (x < 6) ? 5 : 4;
    const bool hast = (wave < 2 * ng);
    const int jg = wave >> 1, rh = wave & 1;
    const int go = x + 8 * jg;
    const u16* bo = A.o1wT + (size_t)(16 * (hast ? go : 0) + l15) * 608 + koff;
    const int cw = 16 * go + l15;

    for (int i = tid; i < 32 * 616; i += 1024) {
      ((u16*)stgD)[i] = 0;
      ((u16*)stgX)[i] = 0;
    }
    __syncthreads();
    if (tid < 32) stgX[tid][600] = 0x3F80;  // 1.0 bf16 -> picks up bias row
    __syncthreads();

    for (int t = 0; t < 64; ++t) {
      f32x4 p00{}, p01{};
      // ---- P1: deter-GEMM from stgD (deter_{t-1}; zeros at t=0) ----
      if (hasg) {
        for (int kk = 0; kk < 608; kk += 32) {
          short8 a0 = *reinterpret_cast<const short8*>(&stgD[l15][koff + kk]);
          short8 a1 = *reinterpret_cast<const short8*>(&stgD[16 + l15][koff + kk]);
          short8 b0 = *reinterpret_cast<const short8*>(bd0 + kk);
          p00 = MF(a0, b0, p00);
          p01 = MF(a1, b0, p01);
        }
      }
      // ---- P2: wait xF >= t, stage x_t, x-GEMM, store parts, FA ----
      if (tid == 0) {
        int it = 0;
        while ((int)min(fld(FX(2 * h)), fld(FX(2 * h + 1))) < t) {
          if (++it > POLL_CAP) break;
          __builtin_amdgcn_s_sleep(1);
        }
      }
      __syncthreads();
      for (int idx = tid; idx < 2400; idx += 1024) {  // octets 0..74 (cols<600)
        int r = idx / 75, o = idx - r * 75;
        *reinterpret_cast<short8*>(&stgX[r][o * 8]) =
            ald16B(A.xd + (size_t)(r0 + r) * XDS + o * 8);
      }
      __syncthreads();
      if (hasg) {
        for (int kk = 0; kk < 608; kk += 32) {
          short8 a0 = *reinterpret_cast<const short8*>(&stgX[l15][koff + kk]);
          short8 a1 = *reinterpret_cast<const short8*>(&stgX[16 + l15][koff + kk]);
          short8 b0 = *reinterpret_cast<const short8*>(bx0 + kk);
          p00 = MF(a0, b0, p00);
          p01 = MF(a1, b0, p01);
        }
        if (c0ok) {
#pragma unroll
          for (int i = 0; i < 4; ++i) {
            unsigned h00 = f2bf(p00[i]);
            unsigned h10 = f2bf(p01[i]);
            unsigned o00 = (unsigned)__shfl_xor((int)h00, 1);
            unsigned o10 = (unsigned)__shfl_xor((int)h10, 1);
            if (!(lane & 1)) {
              ast32(A.parts + (size_t)(r0 + crow + i) * PN + c0, h00 | (o00 << 16));
              ast32(A.parts + (size_t)(r0 + 16 + crow + i) * PN + c0, h10 | (o10 << 16));
            }
          }
        }
      }
      __syncthreads();  // drains vmcnt per wave -> stores MALL-visible
      if (tid == 0) fst(FA(fl), (unsigned)(t + 1));
      // ---- P3: wait FD >= t+1, stage deter_t, obs1 slice, FH ----
      if (tid == 0) {
        int it = 0;
        while ((int)min(fld(FD(2 * h)), fld(FD(2 * h + 1))) < (t + 1)) {
          if (++it > POLL_CAP) break;
          __builtin_amdgcn_s_sleep(1);
        }
      }
      __syncthreads();
      for (int idx = tid; idx < 2432; idx += 1024) {  // octets 0..75
        int r = idx / 76, o = idx - r * 76;
        *reinterpret_cast<short8*>(&stgD[r][o * 8]) =
            ald16B(A.xd + (size_t)(r0 + r) * XDS + 600 + o * 8);
      }
      __syncthreads();
      if (hast && go < 38) {
        f32x4 ac{};
        for (int kk = 0; kk < 608; kk += 32)
          ac = MF(*reinterpret_cast<const short8*>(&stgD[rh * 16 + l15][koff + kk]),
                  *reinterpret_cast<const short8*>(bo + kk), ac);
        if (cw < 600) {
#pragma unroll
          for (int i = 0; i < 4; ++i) {
            int grow = r0 + rh * 16 + crow + i;
            float ep = bf2f(__builtin_nontemporal_load(
                A.epre + ((size_t)t * 192 + grow) * 600 + cw));
            unsigned hv = f2bf(eluf(ac[i] + ep));
            unsigned ov = (unsigned)__shfl_xor((int)hv, 1);
            if (!(lane & 1))
              ast32(A.hobs + (size_t)grow * 640 + cw, hv | (ov << 16));
          }
        }
      }
      __syncthreads();  // hobs stores drained
      if (tid == 0) fst(FH(fl), (unsigned)(t + 1));
    }
  } else {
    // ========== BD block: 16 rows R0..R0+15, 16 waves ==========
    const int b = bid - 48, h = b >> 1;
    const int R0 = b * 16;
    u16 (*pl)[PN] = (u16(*)[PN])smem;                       // 57,856
    float (*dsh)[600] = (float(*)[600])(smem + 57856);      // 38,400
    u16 (*hl)[616] = (u16(*)[616])(smem + 96256);           // 19,712
    float (*sl)[68] = (float(*)[68])(smem + 115968);        //  4,352
    u16 (*xa)[72] = (u16(*)[72])(smem + 120320);            //  2,304

    for (int i = tid; i < 16 * 616; i += 1024) ((u16*)hl)[i] = 0;
    for (int i = tid; i < 16 * 72; i += 1024) ((u16*)xa)[i] = 0;
    for (int i = tid; i < 16 * 600; i += 1024) ((float*)dsh)[i] = 0.f;
    __syncthreads();

    for (int t = 0; t < 64; ++t) {
      // ---- per-wave pipelined parts gather ----
      {
        const unsigned tgt = (unsigned)(t + 1);
        const int fw = wave & 7;
        const int rlo = (wave < 8) ? 0 : 8;
        int it = 0;
        while (fld(FA(h * 8 + fw)) < tgt) {
          if (++it > POLL_CAP) break;
          __builtin_amdgcn_s_sleep(1);
        }
        const int J2 = (fw == 0) ? 15 : 14;
        for (int task = lane; task < J2 * 16; task += 64) {
          int j2 = task >> 4;
          int r2 = (task >> 1) & 7, hf = task & 1;
          int col = 16 * (fw + 8 * j2) + hf * 8;
          *reinterpret_cast<short8*>(&pl[rlo + r2][col]) =
              ald16B(A.parts + (size_t)(R0 + rlo + r2) * PN + col);
        }
      }
      __syncthreads();
      // ---- LN + gates + deter: one row per wave (bias fused in parts) ----
      {
        const int rr = wave;
        float s = 0.f;
        for (int j = lane; j < 1800; j += 64) s += bf2f(pl[rr][j]);
#pragma unroll
        for (int o = 32; o; o >>= 1) s += __shfl_xor(s, o);
        float m = s * (1.f / 1800.f);
        float q2 = 0.f;
        for (int j = lane; j < 1800; j += 64) {
          float d = bf2f(pl[rr][j]) - m;
          q2 += d * d;
        }
#pragma unroll
        for (int o = 32; o; o >>= 1) q2 += __shfl_xor(q2, o);
        float rstd = rsqrtf(q2 * (1.f / 1800.f) + 1e-5f);
        for (int j = lane; j < 600; j += 64) {
          float p0 = (bf2f(pl[rr][j]) - m) * rstd * A.lns[j] + A.lnb[j];
          float p1 = (bf2f(pl[rr][600 + j]) - m) * rstd * A.lns[600 + j] + A.lnb[600 + j];
          float p2 =
              (bf2f(pl[rr][1200 + j]) - m) * rstd * A.lns[1200 + j] + A.lnb[1200 + j];
          float r2 = sigf(p0);
          float cd = tanhf(r2 * p1);
          float u = sigf(p2 - 1.f);
          float dn = u * cd + (1.f - u) * dsh[rr][j];
          dsh[rr][j] = dn;
          unsigned hv = f2bf(dn);
          unsigned ov = (unsigned)__shfl_xor((int)hv, 1);
          if (!(lane & 1))
            ast32(A.xd + (size_t)(R0 + rr) * XDS + 600 + j, hv | (ov << 16));
        }
      }
      __syncthreads();  // deter xd stores drained -> publish early
      if (tid == 0) fst(FD(b), (unsigned)(t + 1));
      // ---- off-critical-path: out/dall deter streams ----
      for (int idx = tid; idx < 4800; idx += 1024) {
        int r = idx / 300, j = (idx - r * 300) * 2;
        float f0 = dsh[r][j], f1 = dsh[r][j + 1];
        unsigned pk = (unsigned)f2bf(f0) | ((unsigned)f2bf(f1) << 16);
        size_t orow = (size_t)(R0 + r) * 64 + t;
        __builtin_nontemporal_store(pk, (unsigned*)(A.dall + orow * 640 + j));
        float* ob = A.out + orow * 1392;
        __builtin_nontemporal_store(f0, ob + 96 + j);
        __builtin_nontemporal_store(f1, ob + 97 + j);
        __builtin_nontemporal_store(f0, ob + 792 + j);
        __builtin_nontemporal_store(f1, ob + 793 + j);
      }
      if (tid < 320) {
        int r = tid / 20, qd = tid - r * 20;
        size_t orow = (size_t)(R0 + r) * 64 + t;
        __builtin_nontemporal_store(0u, (unsigned*)(A.dall + orow * 640 + 600 + 2 * qd));
      }
      // ---- wait obs1 producers (FH of my half), gather hobs ----
      {
        const unsigned tgt = (unsigned)(t + 1);
        if (wave == 0) {
          int it = 0;
          for (;;) {
            unsigned v = (lane < 8) ? fld(FH(h * 8 + lane)) : tgt;
            if (__all((int)(v >= tgt))) break;
            if (++it > POLL_CAP) break;
            __builtin_amdgcn_s_sleep(1);
          }
        }
      }
      __syncthreads();
      for (int idx = tid; idx < 1200; idx += 1024) {  // octets 0..74 (cols<600)
        int r = idx / 75, o = idx - r * 75;
        *reinterpret_cast<short8*>(&hl[r][o * 8]) =
            ald16B(A.hobs + (size_t)(R0 + r) * 640 + o * 8);
      }
      __syncthreads();
      // ---- obs2 (waves 0-3) ----
      if (wave < 4) {
        const int n0 = wave * 16;
        const u16* bp = A.o2wT + (size_t)(n0 + l15) * 608 + koff;
        f32x4 ac{};
        for (int kk = 0; kk < 608; kk += 32)
          ac = MF(*reinterpret_cast<const short8*>(&hl[l15][koff + kk]),
                  *reinterpret_cast<const short8*>(bp + kk), ac);
#pragma unroll
        for (int i = 0; i < 4; ++i)
          sl[crow + i][n0 + l15] = ac[i] + A.obs2b[n0 + l15];
      }
      __syncthreads();
      // ---- head outputs + stoch + xa ----
      if (tid < 512) {
        int r = tid >> 5, j = tid & 31;
        size_t orow = (size_t)(R0 + r) * 64 + t;
        float mean = sl[r][j];
        float sd = 2.f * sigf(0.5f * sl[r][32 + j]) + 0.1f;
        float st =
            mean + sd * __builtin_nontemporal_load((const float*)&A.npo[orow * 32 + j]);
        float* ob = A.out + orow * 1392;
        __builtin_nontemporal_store(mean, ob + j);
        __builtin_nontemporal_store(sd, ob + 32 + j);
        __builtin_nontemporal_store(st, ob + 64 + j);
        xa[r][j] = f2bf(st);
      } else if (tid < 768) {
        int r = (tid - 512) >> 4, a2 = tid & 15;
        float av =
            (t < 63)
                ? __builtin_nontemporal_load(
                      (const float*)&A.action[((size_t)(R0 + r) * 64 + t + 1) * 16 + a2])
                : 0.f;
        xa[r][32 + a2] = f2bf(av);
      }
      __syncthreads();
      // ---- img1 -> x(t+1) -> xd ----
      if (t < 63) {
#pragma unroll
        for (int s2 = 0; s2 < 3; ++s2) {
          int g2 = wave + 16 * s2;
          if (g2 < 38) {
            const u16* bp = A.w1pT + (size_t)(g2 * 16 + l15) * 64 + koff;
            f32x4 ax{};
            ax = MF(*reinterpret_cast<const short8*>(&xa[l15][koff]),
                    *reinterpret_cast<const short8*>(bp), ax);
            ax = MF(*reinterpret_cast<const short8*>(&xa[l15][32 + koff]),
                    *reinterpret_cast<const short8*>(bp + 32), ax);
            int cx = g2 * 16 + l15;
            float bi = (cx < 600) ? A.img1b[cx] : 0.f;
#pragma unroll
            for (int i = 0; i < 4; ++i) {
              unsigned hv = f2bf(eluf(ax[i] + bi));
              unsigned ov = (unsigned)__shfl_xor((int)hv, 1);
              if (!(lane & 1) && cx < 600)
                ast32(A.xd + (size_t)(R0 + crow + i) * XDS + cx, hv | (ov << 16));
            }
          }
        }
        __syncthreads();  // x stores drained
        if (tid == 0) fst(FX(b), (unsigned)(t + 1));
      }
    }
  }
}

// ---------------- launch ----------------
extern "C" void kernel_launch(void* const* d_in, const int* in_sizes, int n_in,
                              void* d_out, int out_size, void* d_ws, size_t ws_size,
                              hipStream_t stream) {
  (void)in_sizes; (void)n_in; (void)out_size; (void)ws_size;
  const float* action = (const float*)d_in[0];
  const float* embed = (const float*)d_in[1];
  const float* npr = (const float*)d_in[2];
  const float* npo = (const float*)d_in[3];
  const float* img1w = (const float*)d_in[4];
  const float* img1b = (const float*)d_in[5];
  const float* gruw = (const float*)d_in[6];
  const float* grub = (const float*)d_in[7];
  const float* lns = (const float*)d_in[8];
  const float* lnb = (const float*)d_in[9];
  const float* img2w = (const float*)d_in[10];
  const float* img2b = (const float*)d_in[11];
  const float* img3w = (const float*)d_in[12];
  const float* img3b = (const float*)d_in[13];
  const float* obs1w = (const float*)d_in[14];
  const float* obs1b = (const float*)d_in[15];
  const float* obs2w = (const float*)d_in[16];
  const float* obs2b = (const float*)d_in[17];
  float* out = (float*)d_out;
  char* ws = (char*)d_ws;

  size_t off = 0;
  auto alloc = [&](size_t bytes) {
    size_t o = off;
    off += (bytes + 255) & ~(size_t)255;
    return o;
  };
  size_t o_flags = alloc(11264 * 4);
  size_t o_embed = alloc(12288ull * 1024 * 2);  // reused as dall (12288x640)
  size_t o_epre = alloc(12288ull * 600 * 2);    // reused (with o_wemb) as h_img
  size_t o_wemb = alloc(1024ull * 600 * 2);
  size_t o_wxT = alloc(1808ull * 608 * 2);
  size_t o_wdT = alloc(1808ull * 608 * 2);
  size_t o_o1wT = alloc(608ull * 608 * 2);
  size_t o_o2wT = alloc(64ull * 608 * 2);
  size_t o_w1pT = alloc(640ull * 64 * 2);
  size_t o_i2w = alloc(640ull * 600 * 2);
  size_t o_i3w = alloc(640ull * 64 * 2);
  size_t o_xd = alloc(192ull * XDS * 2);
  size_t o_parts = alloc(192ull * PN * 2);
  size_t o_hobs = alloc(192ull * 640 * 2);

  unsigned* flags = (unsigned*)(ws + o_flags);
  u16* embed_bf = (u16*)(ws + o_embed);
  u16* dall = (u16*)(ws + o_embed);
  u16* epre = (u16*)(ws + o_epre);
  u16* himg = (u16*)(ws + o_epre);
  u16* wemb = (u16*)(ws + o_wemb);
  u16* wxT = (u16*)(ws + o_wxT);
  u16* wdT = (u16*)(ws + o_wdT);
  u16* o1wT = (u16*)(ws + o_o1wT);
  u16* o2wT = (u16*)(ws + o_o2wT);
  u16* w1pT = (u16*)(ws + o_w1pT);
  u16* i2wb = (u16*)(ws + o_i2w);
  u16* i3wb = (u16*)(ws + o_i3w);
  u16* xd = (u16*)(ws + o_xd);
  u16* parts = (u16*)(ws + o_parts);
  u16* hobs = (u16*)(ws + o_hobs);

  auto cgr = [](size_t total) {
    size_t g = (total + 255) / 256;
    return (unsigned)(g > 4096 ? 4096 : g);
  };

  // setup conversions
  conv_pad<<<cgr(12288ull * 1024), 256, 0, stream>>>(embed, embed_bf, 12288, 1024, 12288, 0);
  conv_pad<<<cgr(1024ull * 600), 256, 0, stream>>>(obs1w, wemb, 1024, 600, 1024, 600);
  conv_pad<<<cgr(640ull * 600), 256, 0, stream>>>(img2w, i2wb, 600, 600, 640, 0);
  conv_pad<<<cgr(640ull * 64), 256, 0, stream>>>(img3w, i3wb, 600, 64, 640, 0);
  conv_T<<<cgr(1808ull * 608), 256, 0, stream>>>(gruw, wxT, 600, 1800, 608, 1808, 0);
  conv_T<<<cgr(1808ull * 608), 256, 0, stream>>>(gruw, wdT, 600, 1800, 608, 1808, 600);
  conv_brow<<<8, 256, 0, stream>>>(grub, wxT);
  conv_T<<<cgr(608ull * 608), 256, 0, stream>>>(obs1w, o1wT, 600, 600, 608, 608, 0);
  conv_T<<<cgr(64ull * 608), 256, 0, stream>>>(obs2w, o2wT, 600, 64, 608, 64, 0);
  conv_T<<<cgr(640ull * 64), 256, 0, stream>>>(img1w, w1pT, 48, 600, 64, 640, 0);

  k_init<<<192, 256, 0, stream>>>(action, img1w, img1b, xd, flags);

  // epre[t][b][600] = embed @ obs1_w[600:,:] + obs1_b   (bf16, t-major)
  gemm64<4><<<dim3(10, 192), 256, 0, stream>>>(embed_bf, 1024, wemb, 600, obs1b,
                                               epre, 600, 600, 600, 1024);

  // scan: 48 A blocks (GRU + obs1) + 12 BD blocks, 1024 threads each
  ScanArgs sa;
  sa.xd = xd; sa.parts = parts; sa.hobs = hobs;
  sa.wdT = wdT; sa.wxT = wxT; sa.lns = lns; sa.lnb = lnb;
  sa.dall = dall; sa.out = out;
  sa.o1wT = o1wT; sa.epre = epre;
  sa.o2wT = o2wT; sa.obs2b = obs2b; sa.npo = npo;
  sa.w1pT = w1pT; sa.img1b = img1b; sa.action = action;
  sa.flags = flags;
  scan64<<<60, 1024, 0, stream>>>(sa);

  // batched prior: h_img = elu(deter_all @ img2_w + img2_b), then img3 head
  gemm64<2><<<dim3(10, 192), 256, 0, stream>>>(dall, 640, i2wb, 600, img2b,
                                               himg, 640, 640, 600, 640);
  head_prior<<<192, 256, 0, stream>>>(himg, i3wb, img3b, npr, out);
}